// Round 13
// baseline (343.831 us; speedup 1.0000x reference)
//
#include <hip/hip_runtime.h>
#include <math.h>

#define B_    2
#define S_    2048
#define E_    2048
#define H_    32
#define HKV_  8
#define D_    64

typedef __bf16 bf16x8 __attribute__((ext_vector_type(8)));
typedef float  f32x4  __attribute__((ext_vector_type(4)));
typedef float  f32x16 __attribute__((ext_vector_type(16)));
typedef unsigned int u32x2 __attribute__((ext_vector_type(2)));
typedef unsigned int u32x4 __attribute__((ext_vector_type(4)));

#define GPTR(x) ((const __attribute__((address_space(1))) void*)(x))
#define LPTR(x) ((__attribute__((address_space(3))) void*)(x))

// 0.125 * log2(e): folded into Q so attention softmax is exp2-direct.
#define QK_SCALE_LOG2E 0.18033688011112042f

// ---------------------------------------------------------------------------
// Fused prep: fp32->bf16 convert of x (blocks 0..4095) + all 4 weight
// transposes (blocks 4096..14335). Independent outputs, both memory-bound:
// one dispatch overlaps their BW usage and kills a launch gap.
// ---------------------------------------------------------------------------
__global__ __launch_bounds__(256) void prep_kernel(
    const float* __restrict__ x, __bf16* __restrict__ xb,
    const float* __restrict__ wq, const float* __restrict__ wk,
    const float* __restrict__ wv, const float* __restrict__ wo,
    __bf16* __restrict__ wT, __bf16* __restrict__ woT)
{
    __shared__ float tile[32][33];
    if (blockIdx.x < 4096) {
        const int i = blockIdx.x * 256 + threadIdx.x;
        const float4 a = ((const float4*)x)[i * 2];
        const float4 b = ((const float4*)x)[i * 2 + 1];
        bf16x8 o;
        o[0] = (__bf16)a.x; o[1] = (__bf16)a.y; o[2] = (__bf16)a.z; o[3] = (__bf16)a.w;
        o[4] = (__bf16)b.x; o[5] = (__bf16)b.y; o[6] = (__bf16)b.z; o[7] = (__bf16)b.w;
        ((bf16x8*)xb)[i] = o;
        return;
    }
    const int lin = blockIdx.x - 4096;      // 0..10239
    const int xi  = lin % 160;              // matrix col-tile
    const int ky  = lin / 160;              // 0..63 k-tile
    const float* in; __bf16* out; int N, xt;
    if (xi < 64)      { in = wq; out = wT;                        N = 2048; xt = xi; }
    else if (xi < 80) { in = wk; out = wT + (size_t)2048 * 2048;  N = 512;  xt = xi - 64; }
    else if (xi < 96) { in = wv; out = wT + (size_t)2560 * 2048;  N = 512;  xt = xi - 80; }
    else              { in = wo; out = woT;                       N = 2048; xt = xi - 96; }
    const int K = 2048;

    const int k0 = ky * 32, n0 = xt * 32;
    const int r  = threadIdx.x >> 3;
    const int c4 = (threadIdx.x & 7) * 4;
    const float4 v = *(const float4*)&in[(size_t)(k0 + r) * N + n0 + c4];
    tile[r][c4 + 0] = v.x; tile[r][c4 + 1] = v.y;
    tile[r][c4 + 2] = v.z; tile[r][c4 + 3] = v.w;
    __syncthreads();
    ushort4 o;
    __bf16 h0 = (__bf16)tile[c4 + 0][r]; o.x = __builtin_bit_cast(unsigned short, h0);
    __bf16 h1 = (__bf16)tile[c4 + 1][r]; o.y = __builtin_bit_cast(unsigned short, h1);
    __bf16 h2 = (__bf16)tile[c4 + 2][r]; o.z = __builtin_bit_cast(unsigned short, h2);
    __bf16 h3 = (__bf16)tile[c4 + 3][r]; o.w = __builtin_bit_cast(unsigned short, h3);
    *(ushort4*)&out[(size_t)(n0 + r) * K + k0 + c4] = o;
}

// ---------------------------------------------------------------------------
// T3-minimum double-buffered GEMM (catalog recipe): BK=64, 2 LDS slots,
// 512 thr = 8 waves (2M x 4N). Per K-tile:
//   { stage(T+1 -> other slot); compute(T); vmcnt(0); barrier }
// R12 lesson: the lever is LDS <= 80 KB -> 2 blocks/CU so a co-resident
// block hides the vmcnt(0)+barrier drain (m233 stall). R10's failure was
// a 96 KB ring (still 1 block/CU) paying the small-tile cost for nothing.
// LDS swizzle: 16B chunk c ^= (row&7) both-sides (m97-proven).
// ---------------------------------------------------------------------------
template<int BM, int BN> struct DB {
    static constexpr int ASLOT = BM * 64;
    static constexpr int BSLOT = BN * 64;
    static constexpr int SLOT  = ASLOT + BSLOT;
    static constexpr int AG    = BM / 64;     // A stage instrs (64 rows each)
    static constexpr int BG    = BN / 64;
    static constexpr int MI    = BM / 32;     // A frags per wave
    static constexpr int NJ    = BN / 64;     // B frags per wave
};

template<int BM, int BN>
__device__ __forceinline__ void stage64(
    const __bf16* __restrict__ A, const __bf16* __restrict__ Bt,
    int m0, int n0, int K, int T, __bf16* sl, int t)
{
    using G = DB<BM, BN>;
    const int k0 = T * 64;
    const int rs = t >> 3;       // 0..63 row-in-group
    const int cp = t & 7;        // physical 16B chunk within 128B row
#pragma unroll
    for (int g = 0; g < G::AG; ++g) {
        const int row = g * 64 + rs;
        const int cs  = cp ^ (row & 7);          // pre-swizzled source chunk
        __builtin_amdgcn_global_load_lds(
            GPTR(A + (size_t)(m0 + row) * K + k0 + cs * 8),
            LPTR(sl + g * 4096 + t * 8), 16, 0, 0);
    }
#pragma unroll
    for (int g = 0; g < G::BG; ++g) {
        const int row = g * 64 + rs;
        const int cs  = cp ^ (row & 7);
        __builtin_amdgcn_global_load_lds(
            GPTR(Bt + (size_t)(n0 + row) * K + k0 + cs * 8),
            LPTR(sl + G::ASLOT + g * 4096 + t * 8), 16, 0, 0);
    }
}

template<int BM, int BN>
__device__ __forceinline__ void compute64(
    const __bf16* sl, int wrow, int wcol, int col, int quad,
    f32x4 acc[DB<BM, BN>::MI][DB<BM, BN>::NJ])
{
    using G = DB<BM, BN>;
#pragma unroll
    for (int kk = 0; kk < 2; ++kk) {
        bf16x8 af[G::MI], bfr[G::NJ];
#pragma unroll
        for (int i = 0; i < G::MI; ++i) {
            const int m = wrow + i * 16 + col;
            af[i] = *(const bf16x8*)&sl[m * 64 + (((kk * 4 + quad) ^ (m & 7)) * 8)];
        }
#pragma unroll
        for (int j = 0; j < G::NJ; ++j) {
            const int n = wcol + j * 16 + col;
            bfr[j] = *(const bf16x8*)&sl[G::ASLOT + n * 64 + (((kk * 4 + quad) ^ (n & 7)) * 8)];
        }
        __builtin_amdgcn_s_setprio(1);
#pragma unroll
        for (int i = 0; i < G::MI; ++i)
#pragma unroll
            for (int j = 0; j < G::NJ; ++j)
                acc[i][j] = __builtin_amdgcn_mfma_f32_16x16x32_bf16(
                    af[i], bfr[j], acc[i][j], 0, 0, 0);
        __builtin_amdgcn_s_setprio(0);
    }
}

template<int BM, int BN>
__device__ __forceinline__ void gemm_db_body(
    const __bf16* __restrict__ A, const __bf16* __restrict__ Bt,
    int m0, int n0, int K, __bf16* sL,
    f32x4 acc[DB<BM, BN>::MI][DB<BM, BN>::NJ])
{
    using G = DB<BM, BN>;
    const int t    = threadIdx.x;
    const int lane = t & 63;
    const int col  = lane & 15;
    const int quad = lane >> 4;
    const int w    = t >> 6;
    const int wrow = (w >> 2) * (BM / 2);
    const int wcol = (w & 3) * (BN / 4);
    const int NT   = K / 64;

    stage64<BM, BN>(A, Bt, m0, n0, K, 0, sL, t);
    asm volatile("s_waitcnt vmcnt(0)" ::: "memory");
    __builtin_amdgcn_s_barrier();

#pragma unroll 1
    for (int T = 0; T < NT; ++T) {
        if (T + 1 < NT)
            stage64<BM, BN>(A, Bt, m0, n0, K, T + 1, sL + ((T + 1) & 1) * G::SLOT, t);
        compute64<BM, BN>(sL + (T & 1) * G::SLOT, wrow, wcol, col, quad, acc);
        asm volatile("s_waitcnt vmcnt(0)" ::: "memory");
        __builtin_amdgcn_s_barrier();
    }
}

// ---------------------------------------------------------------------------
// QKV GEMM: BM=128, BN=192, BK=64 -> LDS 80 KiB -> 2 blocks/CU (R12, kept).
// Grid 32x16 = 512 blocks = exactly 2 full rounds (100% fill).
// ---------------------------------------------------------------------------
__global__ __launch_bounds__(512, 2) void gemm_qkv_kernel(
    const __bf16* __restrict__ xb, const __bf16* __restrict__ wT,
    const float* __restrict__ fc, const float* __restrict__ fs,
    __bf16* __restrict__ qb, __bf16* __restrict__ kb, __bf16* __restrict__ vb)
{
    __shared__ __bf16 sL[2 * DB<128, 192>::SLOT];   // 80 KiB
    f32x4 acc[4][3];
#pragma unroll
    for (int i = 0; i < 4; ++i)
#pragma unroll
        for (int j = 0; j < 3; ++j) acc[i][j] = (f32x4){0.f, 0.f, 0.f, 0.f};

    // T1: bijective XCD swizzle over 512 blocks.
    const int lin     = blockIdx.x;
    const int logical = (lin & 7) * 64 + (lin >> 3);
    const int m0      = (logical >> 4) * 128;
    const int n0      = (logical & 15) * 192;

    gemm_db_body<128, 192>(xb, wT, m0, n0, E_, sL, acc);

    const int t    = threadIdx.x;
    const int lane = t & 63;
    const int col  = lane & 15;
    const int quad = lane >> 4;
    const int w    = t >> 6;
    const int wrow = (w >> 2) * 64;
    const int wcol = (w & 3) * 48;
#pragma unroll
    for (int i = 0; i < 4; ++i)
#pragma unroll
        for (int j = 0; j < 3; ++j)
#pragma unroll
            for (int r = 0; r < 4; ++r) {
                const int m = m0 + wrow + i * 16 + quad * 4 + r;
                const int n = n0 + wcol + j * 16 + col;   // 0..3071 global col
                float val = acc[i][j][r];
                if (n < 2560) {                            // Q or K: rope
                    if (n < 2048) val *= QK_SCALE_LOG2E;   // Q: fold scale
                    const int   s    = m & (S_ - 1);
                    const int   pair = (n & 63) >> 1;
                    const float c    = fc[s * 32 + pair];
                    const float sn   = fs[s * 32 + pair];
                    const float oth  = __shfl_xor(val, 1);
                    val = (lane & 1) ? (oth * sn + val * c)
                                     : (val * c - oth * sn);
                }
                if (n < 2048)
                    qb[(size_t)m * (H_ * D_) + n] = (__bf16)val;
                else if (n < 2560)
                    kb[(size_t)m * (HKV_ * D_) + (n - 2048)] = (__bf16)val;
                else
                    vb[(size_t)m * (HKV_ * D_) + (n - 2560)] = (__bf16)val;
            }
}

// ---------------------------------------------------------------------------
// Output GEMM: BM=128, BN=128 -> LDS 64 KiB -> 2 blocks/CU (R12 mechanism).
// Grid 32x16 = 512 blocks = exactly 2 full rounds (100% fill). Bias.
// ---------------------------------------------------------------------------
__global__ __launch_bounds__(512, 2) void gemm_out_kernel(
    const __bf16* __restrict__ ob, const __bf16* __restrict__ woT,
    const float* __restrict__ bias, float* __restrict__ out)
{
    __shared__ __bf16 sL[2 * DB<128, 128>::SLOT];   // 64 KiB
    f32x4 acc[4][2];
#pragma unroll
    for (int i = 0; i < 4; ++i)
#pragma unroll
        for (int j = 0; j < 2; ++j) acc[i][j] = (f32x4){0.f, 0.f, 0.f, 0.f};

    // T1: bijective XCD swizzle over 512 blocks.
    const int lin     = blockIdx.x;
    const int logical = (lin & 7) * 64 + (lin >> 3);
    const int n0      = (logical % 16) * 128;
    const int m0      = (logical / 16) * 128;

    gemm_db_body<128, 128>(ob, woT, m0, n0, H_ * D_, sL, acc);

    const int t    = threadIdx.x;
    const int lane = t & 63;
    const int col  = lane & 15;
    const int quad = lane >> 4;
    const int w    = t >> 6;
    const int wrow = (w >> 2) * 64;
    const int wcol = (w & 3) * 32;
#pragma unroll
    for (int i = 0; i < 4; ++i)
#pragma unroll
        for (int j = 0; j < 2; ++j)
#pragma unroll
            for (int r = 0; r < 4; ++r) {
                const int m = m0 + wrow + i * 16 + quad * 4 + r;
                const int n = n0 + wcol + j * 16 + col;
                out[(size_t)m * E_ + n] = acc[i][j][r] + bias[n];
            }
}

// ---------------------------------------------------------------------------
// MFMA flash attention (R6 body: ~107 µs, 116 VGPR, no spill).
// Dual-chain QK^T; V reads hoisted; exp2-direct; cvt_pk+permlane pack.
// __launch_bounds__(256) ONLY — forcing 4 waves/EU or 64q/wave spills
// 245-650 MB scratch (R3/R7/R8). ~180 VGPR+AGPR demand is structural.
// ---------------------------------------------------------------------------
struct StageRegs {
    bf16x8  k0, k1;
    ushort4 va0, vc0, va1, vc1;
};

__device__ __forceinline__ void stage_load(
    StageRegs& r, const __bf16* kbase, const __bf16* vbase, int j0,
    int kkey, int kd, int vkp, int vdg)
{
    const int KSTR = HKV_ * D_;   // 512
    const __bf16* kr = kbase + (size_t)(j0 + kkey) * KSTR + kd;
    r.k0 = ((const bf16x8*)kr)[0];
    r.k1 = ((const bf16x8*)kr)[1];
    const __bf16* v0 = vbase + (size_t)(j0 + vkp) * KSTR + vdg;
    r.va0 = *(const ushort4*)(v0);
    r.vc0 = *(const ushort4*)(v0 + KSTR);
    r.va1 = *(const ushort4*)(v0 + 32);
    r.vc1 = *(const ushort4*)(v0 + KSTR + 32);
}

__device__ __forceinline__ void stage_write(
    const StageRegs& r, __bf16 (*sK)[72], __bf16 (*sVT)[72],
    int kkey, int kd, int vkp, int vdg)
{
    *(bf16x8*)&sK[kkey][kd]     = r.k0;
    *(bf16x8*)&sK[kkey][kd + 8] = r.k1;
    *(unsigned int*)&sVT[vdg + 0][vkp]      = ((unsigned)r.vc0.x << 16) | r.va0.x;
    *(unsigned int*)&sVT[vdg + 1][vkp]      = ((unsigned)r.vc0.y << 16) | r.va0.y;
    *(unsigned int*)&sVT[vdg + 2][vkp]      = ((unsigned)r.vc0.z << 16) | r.va0.z;
    *(unsigned int*)&sVT[vdg + 3][vkp]      = ((unsigned)r.vc0.w << 16) | r.va0.w;
    *(unsigned int*)&sVT[vdg + 32 + 0][vkp] = ((unsigned)r.vc1.x << 16) | r.va1.x;
    *(unsigned int*)&sVT[vdg + 32 + 1][vkp] = ((unsigned)r.vc1.y << 16) | r.va1.y;
    *(unsigned int*)&sVT[vdg + 32 + 2][vkp] = ((unsigned)r.vc1.z << 16) | r.va1.z;
    *(unsigned int*)&sVT[vdg + 32 + 3][vkp] = ((unsigned)r.vc1.w << 16) | r.va1.w;
}

__device__ __forceinline__ bf16x8 pack_pa(const f32x16& p, int i0)
{
    unsigned a0, a1, a2, a3;
    asm("v_cvt_pk_bf16_f32 %0, %1, %2" : "=v"(a0) : "v"(p[i0 + 0]), "v"(p[i0 + 1]));
    asm("v_cvt_pk_bf16_f32 %0, %1, %2" : "=v"(a1) : "v"(p[i0 + 2]), "v"(p[i0 + 3]));
    asm("v_cvt_pk_bf16_f32 %0, %1, %2" : "=v"(a2) : "v"(p[i0 + 4]), "v"(p[i0 + 5]));
    asm("v_cvt_pk_bf16_f32 %0, %1, %2" : "=v"(a3) : "v"(p[i0 + 6]), "v"(p[i0 + 7]));
    const u32x2 s02 = __builtin_amdgcn_permlane32_swap(a0, a2, false, false);
    const u32x2 s13 = __builtin_amdgcn_permlane32_swap(a1, a3, false, false);
    return __builtin_bit_cast(bf16x8, (u32x4){s02[0], s13[0], s02[1], s13[1]});
}

__device__ __forceinline__ void attn_tile(
    const __bf16 (*sK)[72], const __bf16 (*sVT)[72],
    const bf16x8* bQ, int lq, int hi,
    f32x16& O0, f32x16& O1, float& lsum)
{
    f32x16 p0, p1;
#pragma unroll
    for (int i = 0; i < 16; ++i) { p0[i] = 0.f; p1[i] = 0.f; }
    __builtin_amdgcn_s_setprio(1);
#pragma unroll
    for (int ks = 0; ks < 4; ++ks) {
        const bf16x8 aK0 = *(const bf16x8*)&sK[lq][ks * 16 + hi * 8];
        const bf16x8 aK1 = *(const bf16x8*)&sK[32 + lq][ks * 16 + hi * 8];
        p0 = __builtin_amdgcn_mfma_f32_32x32x16_bf16(aK0, bQ[ks], p0, 0, 0, 0);
        p1 = __builtin_amdgcn_mfma_f32_32x32x16_bf16(aK1, bQ[ks], p1, 0, 0, 0);
    }
    __builtin_amdgcn_s_setprio(0);

    bf16x8 vbf[8];
#pragma unroll
    for (int ks = 0; ks < 4; ++ks) {
        vbf[ks * 2]     = *(const bf16x8*)&sVT[lq][ks * 16 + hi * 8];
        vbf[ks * 2 + 1] = *(const bf16x8*)&sVT[32 + lq][ks * 16 + hi * 8];
    }

    float ps = 0.f;
#pragma unroll
    for (int i = 0; i < 16; ++i) {
        p0[i] = __builtin_amdgcn_exp2f(p0[i]);
        p1[i] = __builtin_amdgcn_exp2f(p1[i]);
        ps += p0[i] + p1[i];
    }
    lsum += ps;

    bf16x8 pa[4];
    pa[0] = pack_pa(p0, 0);
    pa[1] = pack_pa(p0, 8);
    pa[2] = pack_pa(p1, 0);
    pa[3] = pack_pa(p1, 8);

    __builtin_amdgcn_s_setprio(1);
#pragma unroll
    for (int ks = 0; ks < 4; ++ks) {
        O0 = __builtin_amdgcn_mfma_f32_32x32x16_bf16(pa[ks], vbf[ks * 2],     O0, 0, 0, 0);
        O1 = __builtin_amdgcn_mfma_f32_32x32x16_bf16(pa[ks], vbf[ks * 2 + 1], O1, 0, 0, 0);
    }
    __builtin_amdgcn_s_setprio(0);
}

__global__ __launch_bounds__(256) void attn_kernel(
    const __bf16* __restrict__ qw, const __bf16* __restrict__ kw,
    const __bf16* __restrict__ vw, __bf16* __restrict__ ow)
{
    __shared__ __bf16 sK0[64][72], sVT0[64][72];
    __shared__ __bf16 sK1[64][72], sVT1[64][72];

    const int t    = threadIdx.x;
    const int lane = t & 63;
    const int w    = t >> 6;
    const int lq   = lane & 31;
    const int hi   = lane >> 5;

    const int bh  = blockIdx.y;
    const int b   = bh >> 5;
    const int h   = bh & 31;
    const int kvh = h >> 2;
    const int q0  = blockIdx.x * 128 + w * 32;

    bf16x8 bQ[4];
    {
        const __bf16* qrow = qw + (((size_t)b * S_ + q0 + lq) * H_ + h) * D_;
#pragma unroll
        for (int ks = 0; ks < 4; ++ks)
            bQ[ks] = *(const bf16x8*)(qrow + ks * 16 + hi * 8);
    }

    f32x16 O0, O1;
#pragma unroll
    for (int i = 0; i < 16; ++i) { O0[i] = 0.f; O1[i] = 0.f; }
    float lsum = 0.f;

    const __bf16* kbase = kw + ((size_t)b * S_ * HKV_ + kvh) * D_;
    const __bf16* vbase = vw + ((size_t)b * S_ * HKV_ + kvh) * D_;
    const int kkey = t >> 2,        kd  = (t & 3) * 16;
    const int vkp  = (t & 31) * 2,  vdg = (t >> 5) * 4;

    StageRegs sr;
    stage_load(sr, kbase, vbase, 0, kkey, kd, vkp, vdg);
    stage_write(sr, sK0, sVT0, kkey, kd, vkp, vdg);
    __syncthreads();

#pragma unroll 1
    for (int j0 = 0; j0 < S_; j0 += 128) {
        StageRegs nx;
        stage_load(nx, kbase, vbase, j0 + 64, kkey, kd, vkp, vdg);
        attn_tile(sK0, sVT0, bQ, lq, hi, O0, O1, lsum);
        stage_write(nx, sK1, sVT1, kkey, kd, vkp, vdg);
        __syncthreads();
        if (j0 + 128 < S_)
            stage_load(nx, kbase, vbase, j0 + 128, kkey, kd, vkp, vdg);
        attn_tile(sK1, sVT1, bQ, lq, hi, O0, O1, lsum);
        if (j0 + 128 < S_)
            stage_write(nx, sK0, sVT0, kkey, kd, vkp, vdg);
        __syncthreads();
    }

    lsum += __shfl_xor(lsum, 32);
    const float inv = 1.0f / lsum;

#pragma unroll
    for (int r = 0; r < 16; ++r) {
        const int   qr = (r & 3) + 8 * (r >> 2) + 4 * hi;
        const float li = __shfl(inv, qr);
        __bf16* orow = ow + (((size_t)b * S_ + q0 + qr) * H_ + h) * D_;
        orow[lq]      = (__bf16)(O0[r] * li);
        orow[32 + lq] = (__bf16)(O1[r] * li);
    }
}

// ---------------------------------------------------------------------------
extern "C" void kernel_launch(void* const* d_in, const int* in_sizes, int n_in,
                              void* d_out, int out_size, void* d_ws, size_t ws_size,
                              hipStream_t stream)
{
    const float* x  = (const float*)d_in[0];
    const float* fc = (const float*)d_in[2];
    const float* fs = (const float*)d_in[3];
    const float* wq = (const float*)d_in[4];
    const float* wk = (const float*)d_in[5];
    const float* wv = (const float*)d_in[6];
    const float* wo = (const float*)d_in[7];
    const float* obias = (const float*)d_in[8];
    float* out = (float*)d_out;

    __bf16* ws  = (__bf16*)d_ws;
    __bf16* xb  = ws;                                    // 4096*2048
    __bf16* wT  = xb  + (size_t)4096 * 2048;             // 3072*2048 [wq^T|wk^T|wv^T]
    __bf16* woT = wT  + (size_t)3072 * 2048;             // 2048*2048
    __bf16* qb  = woT + (size_t)2048 * 2048;             // B,S,H,D
    __bf16* kb  = qb  + (size_t)B_ * S_ * H_ * D_;       // B,S,HKV,D
    __bf16* vb  = kb  + (size_t)B_ * S_ * HKV_ * D_;
    __bf16* obf = vb  + (size_t)B_ * S_ * HKV_ * D_;     // B,S,H,D

    prep_kernel<<<4096 + 160 * 64, 256, 0, stream>>>(
        x, xb, wq, wk, wv, wo, wT, woT);

    gemm_qkv_kernel<<<512, 512, 0, stream>>>(xb, wT, fc, fs, qb, kb, vb);

    attn_kernel<<<dim3(S_ / 128, B_ * H_), 256, 0, stream>>>(qb, kb, vb, obf);

    gemm_out_kernel<<<512, 512, 0, stream>>>(obf, woT, obias, out);
}